// Round 4
// baseline (2250.624 us; speedup 1.0000x reference)
//
#include <hip/hip_runtime.h>
#include <hip/hip_fp16.h>

#define NPTS 400000
#define MVOX 300000
#define KK 27
#define KD 8
#define CIN 4
#define C0 32
#define NCLS 19
#define EPS 1e-5f
#define NTILE (MVOX / 16)   // 18750 exact

typedef __attribute__((ext_vector_type(8))) _Float16 half8;
typedef __attribute__((ext_vector_type(4))) float f32x4;

// ---- fp16 pack/unpack helpers ----
__device__ __forceinline__ uint32_t pack2(float a, float b) {
    __half2 h = __floats2half2_rn(a, b);
    return __builtin_bit_cast(uint32_t, h);
}
__device__ __forceinline__ float2 unpack2(uint32_t u) {
    return __half22float2(__builtin_bit_cast(__half2, u));
}
__device__ __forceinline__ void unpack8(uint4 u, float* f) {
    float2 a = unpack2(u.x), b = unpack2(u.y), c = unpack2(u.z), d = unpack2(u.w);
    f[0] = a.x; f[1] = a.y; f[2] = b.x; f[3] = b.y;
    f[4] = c.x; f[5] = c.y; f[6] = d.x; f[7] = d.y;
}
__device__ __forceinline__ uint4 pack8(const float* f) {
    return make_uint4(pack2(f[0], f[1]), pack2(f[2], f[3]),
                      pack2(f[4], f[5]), pack2(f[6], f[7]));
}

// ---------------- voxelization ----------------
__global__ void vox_accum(const float* __restrict__ pf, const int* __restrict__ iq,
                          float* __restrict__ counts, float* __restrict__ vox) {
    int i = blockIdx.x * blockDim.x + threadIdx.x;
    if (i >= NPTS) return;
    int q = iq[i];
    float4 f = *reinterpret_cast<const float4*>(pf + (size_t)i * CIN);
    atomicAdd(&counts[q], 1.0f);
    atomicAdd(&vox[q * CIN + 0], f.x);
    atomicAdd(&vox[q * CIN + 1], f.y);
    atomicAdd(&vox[q * CIN + 2], f.z);
    atomicAdd(&vox[q * CIN + 3], f.w);
}

// vox fp32 -> fp16 rows (8B)
__global__ void vox_div_h(const float4* __restrict__ vox, const float* __restrict__ counts,
                          uint2* __restrict__ voxh) {
    int i = blockIdx.x * blockDim.x + threadIdx.x;
    if (i >= MVOX) return;
    float inv = 1.0f / fmaxf(counts[i], 1.0f);
    float4 v = vox[i];
    voxh[i] = make_uint2(pack2(v.x * inv, v.y * inv), pack2(v.z * inv, v.w * inv));
}

// ------------- W prep: [k][ci][co] fp32 -> per-lane B-fragment fp16 -------------
__global__ void wprep(const float* __restrict__ W0, const float* __restrict__ W1,
                      const float* __restrict__ W2, uint4* __restrict__ Wf) {
    int t = blockIdx.x * blockDim.x + threadIdx.x;
    if (t >= 3 * KK * 128) return;
    int layer = t / (KK * 128);
    int rem = t % (KK * 128);
    int k = rem / 128;
    int h = (rem >> 6) & 1;
    int lane = rem & 63;
    const float* W = (layer == 0) ? W0 : (layer == 1) ? W1 : W2;
    const float* wk = W + k * (C0 * C0);
    int co = h * 16 + (lane & 15);
    int ci0 = (lane >> 4) * 8;
    float f[8];
#pragma unroll
    for (int j = 0; j < 8; j++) f[j] = wk[(ci0 + j) * C0 + co];
    Wf[t] = pack8(f);
}

// ---------------- conv layer 1 (4 -> 32), fp16 in, fp16 raw out ----------------
__global__ void conv_s1_h(const uint2* __restrict__ x, const int* __restrict__ nbrs,
                          const float* __restrict__ W, uint4* __restrict__ out) {
    int i = blockIdx.x * blockDim.x + threadIdx.x;
    if (i >= MVOX) return;
    float acc[C0];
#pragma unroll
    for (int c = 0; c < C0; c++) acc[c] = 0.f;
    const int* nb = nbrs + (size_t)i * KK;
#pragma unroll
    for (int k = 0; k < KK; k++) {
        int idx = nb[k];
        float m = (idx >= 0) ? 1.f : 0.f;
        uint2 r = x[idx < 0 ? 0 : idx];
        float2 ab = unpack2(r.x), cd = unpack2(r.y);
        float xs[4] = {m * ab.x, m * ab.y, m * cd.x, m * cd.y};
        const float* wk = W + k * (CIN * C0);   // k uniform -> scalar loads
#pragma unroll
        for (int j = 0; j < 4; j++) {
#pragma unroll
            for (int co = 0; co < C0; co++) acc[co] += xs[j] * wk[j * C0 + co];
        }
    }
    uint4* o = out + (size_t)i * 4;
#pragma unroll
    for (int p = 0; p < 4; p++) o[p] = pack8(acc + p * 8);
}

// --- conv 32->32 via MFMA, BN(prev)+ReLU fused into the gather path ---
// x: RAW previous conv output; ss: that layer's (scale, shift); out: raw fp16
__global__ __launch_bounds__(256) void conv32_mfma(const uint4* __restrict__ x,
                                                   const int* __restrict__ nbrs,
                                                   const uint4* __restrict__ Wf,
                                                   const float* __restrict__ ss,
                                                   __half* __restrict__ out) {
    const int lane = threadIdx.x & 63;
    const int wid = threadIdx.x >> 6;
    const int tile = blockIdx.x * 4 + wid;
    if (tile >= NTILE) return;
    const int row = lane & 15;          // voxel within tile (A row)
    const int chunk = lane >> 4;        // which 8-ci chunk (A k-group)
    float sc[8], sh[8];
#pragma unroll
    for (int j = 0; j < 8; j++) {
        sc[j] = ss[chunk * 8 + j];
        sh[j] = ss[C0 + chunk * 8 + j];
    }
    const int vr = tile * 16 + row;
    const int* nb = nbrs + (size_t)vr * KK;
    f32x4 acc0 = {0.f, 0.f, 0.f, 0.f}, acc1 = {0.f, 0.f, 0.f, 0.f};
#pragma unroll
    for (int k = 0; k < KK; k++) {
        int idx = nb[k];
        float m = (idx >= 0) ? 1.f : 0.f;
        uint4 ar = x[(size_t)(idx < 0 ? 0 : idx) * 4 + chunk];
        float f[8], g[8];
        unpack8(ar, f);
#pragma unroll
        for (int j = 0; j < 8; j++) g[j] = m * fmaxf(f[j] * sc[j] + sh[j], 0.f);
        half8 a = __builtin_bit_cast(half8, pack8(g));
        half8 b0 = __builtin_bit_cast(half8, Wf[k * 128 + lane]);
        half8 b1 = __builtin_bit_cast(half8, Wf[k * 128 + 64 + lane]);
        acc0 = __builtin_amdgcn_mfma_f32_16x16x32_f16(a, b0, acc0, 0, 0, 0);
        acc1 = __builtin_amdgcn_mfma_f32_16x16x32_f16(a, b1, acc1, 0, 0, 0);
    }
    // D layout: col = lane&15, row = chunk*4 + reg
    __half* obase = out + (size_t)tile * 16 * C0;
    const int col = lane & 15;
#pragma unroll
    for (int r = 0; r < 4; r++) {
        int orow = chunk * 4 + r;
        obase[orow * C0 + col] = __float2half(acc0[r]);
        obase[orow * C0 + 16 + col] = __float2half(acc1[r]);
    }
}

// ---------------- batch norm stats on raw fp16 tensor ----------------
__global__ void bn_stats_h(const uint4* __restrict__ x, float* __restrict__ sums) {
    const int T = MVOX * 4;
    int t0 = blockIdx.x * blockDim.x + threadIdx.x;
    const int stride = gridDim.x * blockDim.x;   // multiple of 4
    float s[8], q[8];
#pragma unroll
    for (int j = 0; j < 8; j++) { s[j] = 0.f; q[j] = 0.f; }
    for (int t = t0; t < T; t += stride) {
        float f[8]; unpack8(x[t], f);
#pragma unroll
        for (int j = 0; j < 8; j++) { s[j] += f[j]; q[j] += f[j] * f[j]; }
    }
#pragma unroll
    for (int off = 32; off >= 4; off >>= 1) {
#pragma unroll
        for (int j = 0; j < 8; j++) {
            s[j] += __shfl_down(s[j], off);
            q[j] += __shfl_down(q[j], off);
        }
    }
    int lane = threadIdx.x & 63;
    if (lane < 4) {
        int cb = lane * 8;
#pragma unroll
        for (int j = 0; j < 8; j++) {
            atomicAdd(&sums[cb + j], s[j]);
            atomicAdd(&sums[C0 + cb + j], q[j]);
        }
    }
}

__global__ void bn_finalize(const float* __restrict__ sums, const float* __restrict__ g,
                            const float* __restrict__ b, float* __restrict__ ss) {
    int c = threadIdx.x;
    if (c >= C0) return;
    float mean = sums[c] * (1.0f / (float)MVOX);
    float var = sums[C0 + c] * (1.0f / (float)MVOX) - mean * mean;
    float sc = g[c] * rsqrtf(var + EPS);
    ss[c] = sc;
    ss[C0 + c] = b[c] - mean * sc;
}

// d = relu( bn_r2(d_raw) + relu(bn_s2(b_raw)) ), in place over d
__global__ void residual_relu_h(uint4* __restrict__ d, const uint4* __restrict__ braw,
                                const float* __restrict__ ss_r2,
                                const float* __restrict__ ss_s2) {
    int t = blockIdx.x * blockDim.x + threadIdx.x;
    if (t >= MVOX * 4) return;
    int cb = (t & 3) * 8;
    float f[8], h[8];
    unpack8(d[t], f); unpack8(braw[t], h);
#pragma unroll
    for (int j = 0; j < 8; j++) {
        float skip = fmaxf(h[j] * ss_s2[cb + j] + ss_s2[C0 + cb + j], 0.f);
        f[j] = fmaxf(f[j] * ss_r2[cb + j] + ss_r2[C0 + cb + j] + skip, 0.f);
    }
    d[t] = pack8(f);
}

// ---------------- devoxelize + classify ----------------
__global__ void devox_classify(const uint4* __restrict__ H, const int4* __restrict__ idxd,
                               const float4* __restrict__ wdev, const float* __restrict__ Wc,
                               const float* __restrict__ bc, float* __restrict__ out) {
    int i = blockIdx.x * blockDim.x + threadIdx.x;
    if (i >= NPTS) return;
    int4 i0 = idxd[2 * i], i1 = idxd[2 * i + 1];
    float4 w0 = wdev[2 * i], w1 = wdev[2 * i + 1];
    int idxs[8] = {i0.x, i0.y, i0.z, i0.w, i1.x, i1.y, i1.z, i1.w};
    float wsv[8] = {w0.x, w0.y, w0.z, w0.w, w1.x, w1.y, w1.z, w1.w};
    float acc[C0];
#pragma unroll
    for (int c = 0; c < C0; c++) acc[c] = 0.f;
#pragma unroll
    for (int k = 0; k < KD; k++) {
        float m = (idxs[k] >= 0) ? wsv[k] : 0.f;
        const uint4* hr = H + (size_t)(idxs[k] < 0 ? 0 : idxs[k]) * 4;
#pragma unroll
        for (int p = 0; p < 4; p++) {
            float f[8]; unpack8(hr[p], f);
#pragma unroll
            for (int j = 0; j < 8; j++) acc[p * 8 + j] += m * f[j];
        }
    }
    float o[NCLS];
#pragma unroll
    for (int c = 0; c < NCLS; c++) o[c] = bc[c];
#pragma unroll
    for (int ci = 0; ci < C0; ci++) {
        float xv = acc[ci];
#pragma unroll
        for (int c = 0; c < NCLS; c++) o[c] += xv * Wc[ci * NCLS + c];
    }
    float* op = out + (size_t)i * NCLS;
#pragma unroll
    for (int c = 0; c < NCLS; c++) op[c] = o[c];
}

extern "C" void kernel_launch(void* const* d_in, const int* in_sizes, int n_in,
                              void* d_out, int out_size, void* d_ws, size_t ws_size,
                              hipStream_t stream) {
    const float* point_fea = (const float*)d_in[0];
    const int*   idx_query = (const int*)d_in[1];
    const int*   nbrs      = (const int*)d_in[2];
    const int*   idx_dev   = (const int*)d_in[3];
    const float* w_dev     = (const float*)d_in[4];
    const float* W_s1      = (const float*)d_in[5];
    const float* W_s2      = (const float*)d_in[6];
    const float* g_s1      = (const float*)d_in[7];
    const float* b_s1      = (const float*)d_in[8];
    const float* g_s2      = (const float*)d_in[9];
    const float* b_s2      = (const float*)d_in[10];
    const float* W_r1      = (const float*)d_in[11];
    const float* W_r2      = (const float*)d_in[12];
    const float* g_r1      = (const float*)d_in[13];
    const float* b_r1      = (const float*)d_in[14];
    const float* g_r2      = (const float*)d_in[15];
    const float* b_r2      = (const float*)d_in[16];
    const float* W_c       = (const float*)d_in[17];
    const float* b_c       = (const float*)d_in[18];
    float* out = (float*)d_out;

    float* ws = (float*)d_ws;
    const size_t M = MVOX;
    float* stats  = ws;                        // 256
    float* ss     = ws + 256;                  // 256
    float* counts = ws + 512;                  // M
    float* vox32  = counts + M;                // 4M fp32  [memset through here]
    uint2* voxh   = (uint2*)(vox32 + 4 * M);   // M * 8B
    uint4* Wf     = (uint4*)((float*)voxh + 2 * M);  // 3*27*128 uint4
    float* bufs   = (float*)Wf + 3 * KK * 128 * 4;
    uint4* A = (uint4*)bufs;                   // raw conv_s1 out (M*32 halfs)
    uint4* B = A + M * 4;                      // raw conv_s2 out
    uint4* C = B + M * 4;                      // raw conv_r1 out
    uint4* D = C + M * 4;                      // raw conv_r2 out -> final H

    hipMemsetAsync(ws, 0, (size_t)(512 + 5 * M) * sizeof(float), stream);

    dim3 blk(256);
    dim3 gN((NPTS + 255) / 256);
    dim3 gM((MVOX + 255) / 256);
    dim3 gE((MVOX * 4 + 255) / 256);
    dim3 gT((NTILE + 3) / 4);
    dim3 gW((3 * KK * 128 + 255) / 256);

    vox_accum<<<gN, blk, 0, stream>>>(point_fea, idx_query, counts, vox32);
    vox_div_h<<<gM, blk, 0, stream>>>((const float4*)vox32, counts, voxh);
    wprep<<<gW, blk, 0, stream>>>(W_s2, W_r1, W_r2, Wf);

    conv_s1_h<<<gM, blk, 0, stream>>>(voxh, nbrs, W_s1, A);
    bn_stats_h<<<512, blk, 0, stream>>>(A, stats + 0);
    bn_finalize<<<1, 64, 0, stream>>>(stats + 0, g_s1, b_s1, ss + 0);

    conv32_mfma<<<gT, blk, 0, stream>>>(A, nbrs, Wf + 0 * KK * 128, ss + 0, (__half*)B);
    bn_stats_h<<<512, blk, 0, stream>>>(B, stats + 64);
    bn_finalize<<<1, 64, 0, stream>>>(stats + 64, g_s2, b_s2, ss + 64);

    conv32_mfma<<<gT, blk, 0, stream>>>(B, nbrs, Wf + 1 * KK * 128, ss + 64, (__half*)C);
    bn_stats_h<<<512, blk, 0, stream>>>(C, stats + 128);
    bn_finalize<<<1, 64, 0, stream>>>(stats + 128, g_r1, b_r1, ss + 128);

    conv32_mfma<<<gT, blk, 0, stream>>>(C, nbrs, Wf + 2 * KK * 128, ss + 128, (__half*)D);
    bn_stats_h<<<512, blk, 0, stream>>>(D, stats + 192);
    bn_finalize<<<1, 64, 0, stream>>>(stats + 192, g_r2, b_r2, ss + 192);

    residual_relu_h<<<gE, blk, 0, stream>>>(D, B, ss + 192, ss + 64);

    devox_classify<<<gN, blk, 0, stream>>>(D, (const int4*)idx_dev,
                                           (const float4*)w_dev, W_c, b_c, out);
}

// Round 5
// 798.820 us; speedup vs baseline: 2.8174x; 2.8174x over previous
//
#include <hip/hip_runtime.h>
#include <hip/hip_fp16.h>

#define NPTS 400000
#define MVOX 300000
#define KK 27
#define KD 8
#define CIN 4
#define C0 32
#define NCLS 19
#define EPS 1e-5f
#define NTILE (MVOX / 16)   // 18750 exact
#define NPART 512           // bn stage-1 blocks

typedef __attribute__((ext_vector_type(8))) _Float16 half8;
typedef __attribute__((ext_vector_type(4))) float f32x4;

// ---- fp16 pack/unpack helpers ----
__device__ __forceinline__ uint32_t pack2(float a, float b) {
    __half2 h = __floats2half2_rn(a, b);
    return __builtin_bit_cast(uint32_t, h);
}
__device__ __forceinline__ float2 unpack2(uint32_t u) {
    return __half22float2(__builtin_bit_cast(__half2, u));
}
__device__ __forceinline__ void unpack8(uint4 u, float* f) {
    float2 a = unpack2(u.x), b = unpack2(u.y), c = unpack2(u.z), d = unpack2(u.w);
    f[0] = a.x; f[1] = a.y; f[2] = b.x; f[3] = b.y;
    f[4] = c.x; f[5] = c.y; f[6] = d.x; f[7] = d.y;
}
__device__ __forceinline__ uint4 pack8(const float* f) {
    return make_uint4(pack2(f[0], f[1]), pack2(f[2], f[3]),
                      pack2(f[4], f[5]), pack2(f[6], f[7]));
}

// ---------------- voxelization ----------------
__global__ void vox_accum(const float* __restrict__ pf, const int* __restrict__ iq,
                          float* __restrict__ counts, float* __restrict__ vox) {
    int i = blockIdx.x * blockDim.x + threadIdx.x;
    if (i >= NPTS) return;
    int q = iq[i];
    float4 f = *reinterpret_cast<const float4*>(pf + (size_t)i * CIN);
    atomicAdd(&counts[q], 1.0f);
    atomicAdd(&vox[q * CIN + 0], f.x);
    atomicAdd(&vox[q * CIN + 1], f.y);
    atomicAdd(&vox[q * CIN + 2], f.z);
    atomicAdd(&vox[q * CIN + 3], f.w);
}

// vox fp32 -> fp16 rows (8B)
__global__ void vox_div_h(const float4* __restrict__ vox, const float* __restrict__ counts,
                          uint2* __restrict__ voxh) {
    int i = blockIdx.x * blockDim.x + threadIdx.x;
    if (i >= MVOX) return;
    float inv = 1.0f / fmaxf(counts[i], 1.0f);
    float4 v = vox[i];
    voxh[i] = make_uint2(pack2(v.x * inv, v.y * inv), pack2(v.z * inv, v.w * inv));
}

// ------------- W prep: [k][ci][co] fp32 -> per-lane B-fragment fp16 -------------
__global__ void wprep(const float* __restrict__ W0, const float* __restrict__ W1,
                      const float* __restrict__ W2, uint4* __restrict__ Wf) {
    int t = blockIdx.x * blockDim.x + threadIdx.x;
    if (t >= 3 * KK * 128) return;
    int layer = t / (KK * 128);
    int rem = t % (KK * 128);
    int k = rem / 128;
    int h = (rem >> 6) & 1;
    int lane = rem & 63;
    const float* W = (layer == 0) ? W0 : (layer == 1) ? W1 : W2;
    const float* wk = W + k * (C0 * C0);
    int co = h * 16 + (lane & 15);
    int ci0 = (lane >> 4) * 8;
    float f[8];
#pragma unroll
    for (int j = 0; j < 8; j++) f[j] = wk[(ci0 + j) * C0 + co];
    Wf[t] = pack8(f);
}

// ---------------- conv layer 1 (4 -> 32), fp16 in, fp16 raw out ----------------
__global__ void conv_s1_h(const uint2* __restrict__ x, const int* __restrict__ nbrs,
                          const float* __restrict__ W, uint4* __restrict__ out) {
    int i = blockIdx.x * blockDim.x + threadIdx.x;
    if (i >= MVOX) return;
    float acc[C0];
#pragma unroll
    for (int c = 0; c < C0; c++) acc[c] = 0.f;
    const int* nb = nbrs + (size_t)i * KK;
#pragma unroll
    for (int k = 0; k < KK; k++) {
        int idx = nb[k];
        float m = (idx >= 0) ? 1.f : 0.f;
        uint2 r = x[idx < 0 ? 0 : idx];
        float2 ab = unpack2(r.x), cd = unpack2(r.y);
        float xs[4] = {m * ab.x, m * ab.y, m * cd.x, m * cd.y};
        const float* wk = W + k * (CIN * C0);   // k uniform -> scalar loads
#pragma unroll
        for (int j = 0; j < 4; j++) {
#pragma unroll
            for (int co = 0; co < C0; co++) acc[co] += xs[j] * wk[j * C0 + co];
        }
    }
    uint4* o = out + (size_t)i * 4;
#pragma unroll
    for (int p = 0; p < 4; p++) o[p] = pack8(acc + p * 8);
}

// --- conv 32->32 via MFMA, BN(prev)+ReLU fused into the gather path ---
__global__ __launch_bounds__(256) void conv32_mfma(const uint4* __restrict__ x,
                                                   const int* __restrict__ nbrs,
                                                   const uint4* __restrict__ Wf,
                                                   const float* __restrict__ ss,
                                                   __half* __restrict__ out) {
    const int lane = threadIdx.x & 63;
    const int wid = threadIdx.x >> 6;
    const int tile = blockIdx.x * 4 + wid;
    if (tile >= NTILE) return;
    const int row = lane & 15;          // voxel within tile (A row)
    const int chunk = lane >> 4;        // which 8-ci chunk (A k-group)
    float sc[8], sh[8];
#pragma unroll
    for (int j = 0; j < 8; j++) {
        sc[j] = ss[chunk * 8 + j];
        sh[j] = ss[C0 + chunk * 8 + j];
    }
    const int vr = tile * 16 + row;
    const int* nb = nbrs + (size_t)vr * KK;
    f32x4 acc0 = {0.f, 0.f, 0.f, 0.f}, acc1 = {0.f, 0.f, 0.f, 0.f};
#pragma unroll
    for (int k = 0; k < KK; k++) {
        int idx = nb[k];
        float m = (idx >= 0) ? 1.f : 0.f;
        uint4 ar = x[(size_t)(idx < 0 ? 0 : idx) * 4 + chunk];
        float f[8], g[8];
        unpack8(ar, f);
#pragma unroll
        for (int j = 0; j < 8; j++) g[j] = m * fmaxf(f[j] * sc[j] + sh[j], 0.f);
        half8 a = __builtin_bit_cast(half8, pack8(g));
        half8 b0 = __builtin_bit_cast(half8, Wf[k * 128 + lane]);
        half8 b1 = __builtin_bit_cast(half8, Wf[k * 128 + 64 + lane]);
        acc0 = __builtin_amdgcn_mfma_f32_16x16x32_f16(a, b0, acc0, 0, 0, 0);
        acc1 = __builtin_amdgcn_mfma_f32_16x16x32_f16(a, b1, acc1, 0, 0, 0);
    }
    // D layout: col = lane&15, row = chunk*4 + reg
    __half* obase = out + (size_t)tile * 16 * C0;
    const int col = lane & 15;
#pragma unroll
    for (int r = 0; r < 4; r++) {
        int orow = chunk * 4 + r;
        obase[orow * C0 + col] = __float2half(acc0[r]);
        obase[orow * C0 + 16 + col] = __float2half(acc1[r]);
    }
}

// ------------- BN stats stage 1: per-block partials, NO global atomics -------------
__global__ __launch_bounds__(256) void bn_partial(const uint4* __restrict__ x,
                                                  float* __restrict__ partials) {
    const int T = MVOX * 4;
    int t0 = blockIdx.x * blockDim.x + threadIdx.x;
    const int stride = NPART * 256;          // multiple of 4 -> octet fixed
    float s[8], q[8];
#pragma unroll
    for (int j = 0; j < 8; j++) { s[j] = 0.f; q[j] = 0.f; }
    for (int t = t0; t < T; t += stride) {
        float f[8]; unpack8(x[t], f);
#pragma unroll
        for (int j = 0; j < 8; j++) { s[j] += f[j]; q[j] += f[j] * f[j]; }
    }
    // lanes l and l+4 share the same octet (tid&3)
#pragma unroll
    for (int off = 32; off >= 4; off >>= 1) {
#pragma unroll
        for (int j = 0; j < 8; j++) {
            s[j] += __shfl_down(s[j], off);
            q[j] += __shfl_down(q[j], off);
        }
    }
    __shared__ float ls[4][64];
    const int w = threadIdx.x >> 6;
    const int lane = threadIdx.x & 63;
    if (lane < 4) {
#pragma unroll
        for (int j = 0; j < 8; j++) {
            ls[w][lane * 8 + j] = s[j];
            ls[w][C0 + lane * 8 + j] = q[j];
        }
    }
    __syncthreads();
    if (threadIdx.x < 64)
        partials[(size_t)blockIdx.x * 64 + threadIdx.x] =
            ls[0][threadIdx.x] + ls[1][threadIdx.x] + ls[2][threadIdx.x] + ls[3][threadIdx.x];
}

// ------------- BN stats stage 2: reduce partials + finalize scale/shift -------------
__global__ __launch_bounds__(256) void bn_reduce_fin(const float* __restrict__ partials,
                                                     const float* __restrict__ g,
                                                     const float* __restrict__ b,
                                                     float* __restrict__ ss) {
    const int tid = threadIdx.x;
    const int c = tid & 63;
    const int part = tid >> 6;               // 0..3
    float acc = 0.f;
    for (int bk = part; bk < NPART; bk += 4) acc += partials[(size_t)bk * 64 + c];
    __shared__ float ls[4][64];
    ls[part][c] = acc;
    __syncthreads();
    __shared__ float fin[64];
    if (tid < 64) fin[tid] = ls[0][tid] + ls[1][tid] + ls[2][tid] + ls[3][tid];
    __syncthreads();
    if (tid < C0) {
        float mean = fin[tid] * (1.0f / (float)MVOX);
        float var = fin[C0 + tid] * (1.0f / (float)MVOX) - mean * mean;
        float sc = g[tid] * rsqrtf(var + EPS);
        ss[tid] = sc;
        ss[C0 + tid] = b[tid] - mean * sc;
    }
}

// d = relu( bn_r2(d_raw) + relu(bn_s2(b_raw)) ), in place over d
__global__ void residual_relu_h(uint4* __restrict__ d, const uint4* __restrict__ braw,
                                const float* __restrict__ ss_r2,
                                const float* __restrict__ ss_s2) {
    int t = blockIdx.x * blockDim.x + threadIdx.x;
    if (t >= MVOX * 4) return;
    int cb = (t & 3) * 8;
    float f[8], h[8];
    unpack8(d[t], f); unpack8(braw[t], h);
#pragma unroll
    for (int j = 0; j < 8; j++) {
        float skip = fmaxf(h[j] * ss_s2[cb + j] + ss_s2[C0 + cb + j], 0.f);
        f[j] = fmaxf(f[j] * ss_r2[cb + j] + ss_r2[C0 + cb + j] + skip, 0.f);
    }
    d[t] = pack8(f);
}

// ---------------- devoxelize + classify ----------------
__global__ void devox_classify(const uint4* __restrict__ H, const int4* __restrict__ idxd,
                               const float4* __restrict__ wdev, const float* __restrict__ Wc,
                               const float* __restrict__ bc, float* __restrict__ out) {
    int i = blockIdx.x * blockDim.x + threadIdx.x;
    if (i >= NPTS) return;
    int4 i0 = idxd[2 * i], i1 = idxd[2 * i + 1];
    float4 w0 = wdev[2 * i], w1 = wdev[2 * i + 1];
    int idxs[8] = {i0.x, i0.y, i0.z, i0.w, i1.x, i1.y, i1.z, i1.w};
    float wsv[8] = {w0.x, w0.y, w0.z, w0.w, w1.x, w1.y, w1.z, w1.w};
    float acc[C0];
#pragma unroll
    for (int c = 0; c < C0; c++) acc[c] = 0.f;
#pragma unroll
    for (int k = 0; k < KD; k++) {
        float m = (idxs[k] >= 0) ? wsv[k] : 0.f;
        const uint4* hr = H + (size_t)(idxs[k] < 0 ? 0 : idxs[k]) * 4;
#pragma unroll
        for (int p = 0; p < 4; p++) {
            float f[8]; unpack8(hr[p], f);
#pragma unroll
            for (int j = 0; j < 8; j++) acc[p * 8 + j] += m * f[j];
        }
    }
    float o[NCLS];
#pragma unroll
    for (int c = 0; c < NCLS; c++) o[c] = bc[c];
#pragma unroll
    for (int ci = 0; ci < C0; ci++) {
        float xv = acc[ci];
#pragma unroll
        for (int c = 0; c < NCLS; c++) o[c] += xv * Wc[ci * NCLS + c];
    }
    float* op = out + (size_t)i * NCLS;
#pragma unroll
    for (int c = 0; c < NCLS; c++) op[c] = o[c];
}

extern "C" void kernel_launch(void* const* d_in, const int* in_sizes, int n_in,
                              void* d_out, int out_size, void* d_ws, size_t ws_size,
                              hipStream_t stream) {
    const float* point_fea = (const float*)d_in[0];
    const int*   idx_query = (const int*)d_in[1];
    const int*   nbrs      = (const int*)d_in[2];
    const int*   idx_dev   = (const int*)d_in[3];
    const float* w_dev     = (const float*)d_in[4];
    const float* W_s1      = (const float*)d_in[5];
    const float* W_s2      = (const float*)d_in[6];
    const float* g_s1      = (const float*)d_in[7];
    const float* b_s1      = (const float*)d_in[8];
    const float* g_s2      = (const float*)d_in[9];
    const float* b_s2      = (const float*)d_in[10];
    const float* W_r1      = (const float*)d_in[11];
    const float* W_r2      = (const float*)d_in[12];
    const float* g_r1      = (const float*)d_in[13];
    const float* b_r1      = (const float*)d_in[14];
    const float* g_r2      = (const float*)d_in[15];
    const float* b_r2      = (const float*)d_in[16];
    const float* W_c       = (const float*)d_in[17];
    const float* b_c       = (const float*)d_in[18];
    float* out = (float*)d_out;

    float* ws = (float*)d_ws;
    const size_t M = MVOX;
    float* ss       = ws;                      // 256
    float* partials = ws + 256;                // NPART*64 = 32768
    float* counts   = partials + NPART * 64;   // M   [memset from here]
    float* vox32    = counts + M;              // 4M fp32
    uint2* voxh     = (uint2*)(vox32 + 4 * M); // M * 8B
    uint4* Wf       = (uint4*)((float*)voxh + 2 * M);  // 3*27*128 uint4
    float* bufs     = (float*)Wf + 3 * KK * 128 * 4;
    uint4* A = (uint4*)bufs;                   // raw conv_s1 out (M*32 halfs)
    uint4* B = A + M * 4;                      // raw conv_s2 out
    uint4* C = B + M * 4;                      // raw conv_r1 out
    uint4* D = C + M * 4;                      // raw conv_r2 out -> final H

    // zero only the atomically-accumulated regions: counts(M)+vox(4M)
    hipMemsetAsync(counts, 0, (size_t)(5 * M) * sizeof(float), stream);

    dim3 blk(256);
    dim3 gN((NPTS + 255) / 256);
    dim3 gM((MVOX + 255) / 256);
    dim3 gE((MVOX * 4 + 255) / 256);
    dim3 gT((NTILE + 3) / 4);
    dim3 gW((3 * KK * 128 + 255) / 256);

    vox_accum<<<gN, blk, 0, stream>>>(point_fea, idx_query, counts, vox32);
    vox_div_h<<<gM, blk, 0, stream>>>((const float4*)vox32, counts, voxh);
    wprep<<<gW, blk, 0, stream>>>(W_s2, W_r1, W_r2, Wf);

    conv_s1_h<<<gM, blk, 0, stream>>>(voxh, nbrs, W_s1, A);
    bn_partial<<<NPART, blk, 0, stream>>>(A, partials);
    bn_reduce_fin<<<1, blk, 0, stream>>>(partials, g_s1, b_s1, ss + 0);

    conv32_mfma<<<gT, blk, 0, stream>>>(A, nbrs, Wf + 0 * KK * 128, ss + 0, (__half*)B);
    bn_partial<<<NPART, blk, 0, stream>>>(B, partials);
    bn_reduce_fin<<<1, blk, 0, stream>>>(partials, g_s2, b_s2, ss + 64);

    conv32_mfma<<<gT, blk, 0, stream>>>(B, nbrs, Wf + 1 * KK * 128, ss + 64, (__half*)C);
    bn_partial<<<NPART, blk, 0, stream>>>(C, partials);
    bn_reduce_fin<<<1, blk, 0, stream>>>(partials, g_r1, b_r1, ss + 128);

    conv32_mfma<<<gT, blk, 0, stream>>>(C, nbrs, Wf + 2 * KK * 128, ss + 128, (__half*)D);
    bn_partial<<<NPART, blk, 0, stream>>>(D, partials);
    bn_reduce_fin<<<1, blk, 0, stream>>>(partials, g_r2, b_r2, ss + 192);

    residual_relu_h<<<gE, blk, 0, stream>>>(D, B, ss + 192, ss + 64);

    devox_classify<<<gN, blk, 0, stream>>>(D, (const int4*)idx_dev,
                                           (const float4*)w_dev, W_c, b_c, out);
}